// Round 2
// baseline (244.283 us; speedup 1.0000x reference)
//
#include <hip/hip_runtime.h>

// SplitEmbedding: out[t, :] = (input_ids[t] in tune_ids) ? train_weight[row(t), :]
//                                                        : base_weight[input_ids[t], :]
// tune_ids SORTED (1024); "later duplicates win" == upper_bound - 1.
//
// v3: batch memory bursts to reduce HBM read<->write turnarounds and improve
// DRAM page locality (v2's search/staging changes were proven neutral -> the
// kernel is pattern-bound, not instruction-bound).
//  - 4 tokens per wave: 12 dwordx4 loads issued back-to-back (12 KB read
//    burst), then 12 NT stores (12 KB contiguous write burst). Block of 8
//    waves covers 32 consecutive rows -> 96 KB contiguous output writes.
//  - token ids fetched as one aligned int4 broadcast load per wave.
//  - search resolved BEFORE payload loads (search cost measured ~0), so each
//    row is read exactly once (no speculative double-read on tune hits).
//  - tune table staged in LDS; heads[] layout keeps round-1 conflict-free.
// Output stores stay nontemporal: 100 MB streaming write must not evict the
// gathered base_weight rows from L2/L3.

#define EMBED_DIM 768
#define WAVES_PER_BLOCK 8
#define BLOCK_THREADS (WAVES_PER_BLOCK * 64)        // 512
#define TPW 4                                       // tokens per wave
#define TOKENS_PER_BLOCK (WAVES_PER_BLOCK * TPW)    // 32
#define NUM_TUNE_C 1024

typedef __attribute__((ext_vector_type(4))) float f4;
typedef __attribute__((ext_vector_type(4))) int   i4;

__global__ __launch_bounds__(BLOCK_THREADS) void split_embedding_kernel(
    const int* __restrict__ input_ids,       // [num_tokens]
    const int* __restrict__ tune_ids,        // [num_tune], sorted ascending
    const float* __restrict__ base_weight,   // [VOCAB, EMBED_DIM]
    const float* __restrict__ train_weight,  // [num_tune, EMBED_DIM]
    float* __restrict__ out,                 // [num_tokens, EMBED_DIM]
    int num_tokens, int num_tune)
{
    __shared__ int lds_tune[NUM_TUNE_C];   // full sorted table
    __shared__ int lds_heads[64];          // tune_ids[s*16] for s = 0..63

    const int wave  = threadIdx.x >> 6;
    const int lane  = threadIdx.x & 63;
    const int tbase = blockIdx.x * TOKENS_PER_BLOCK + wave * TPW;

    // ---- token ids: one aligned int4 broadcast load per wave ----
    int  toks[TPW];
    bool valid[TPW];
    if (tbase + TPW <= num_tokens) {
        const i4 t4 = *(const i4*)(input_ids + tbase);   // tbase % 4 == 0
        toks[0] = t4.x; toks[1] = t4.y; toks[2] = t4.z; toks[3] = t4.w;
        valid[0] = valid[1] = valid[2] = valid[3] = true;
    } else {
        #pragma unroll
        for (int t = 0; t < TPW; ++t) {
            valid[t] = (tbase + t < num_tokens);
            toks[t]  = valid[t] ? input_ids[tbase + t] : 0;
        }
    }

    const float* src[TPW];

    if (num_tune == NUM_TUNE_C) {
        // ---- stage table into LDS (4 KB, aligned int4) ----
        if (threadIdx.x < NUM_TUNE_C / 4) {
            const i4 v = ((const i4*)tune_ids)[threadIdx.x];
            *(i4*)&lds_tune[threadIdx.x * 4] = v;
            if ((threadIdx.x & 3) == 0) lds_heads[threadIdx.x >> 2] = v.x;
        }
        __syncthreads();

        const int h = lds_heads[lane];   // hoisted: shared by all TPW searches

        #pragma unroll
        for (int t = 0; t < TPW; ++t) {
            const int tok = toks[t];
            // Round 1: segment heads (64 x 16 decomposition).
            const unsigned long long b1 = __ballot(h <= tok);
            const int seg = __popcll(b1) - 1;            // wave-uniform
            const float* s = base_weight + (size_t)tok * EMBED_DIM;
            if (seg >= 0) {
                // Round 2: 16 consecutive words, 4x broadcast -> conflict-free.
                const int v2 = lds_tune[(seg << 4) + (lane & 15)];
                const unsigned long long b2 = __ballot(v2 <= tok) & 0xFFFFull;
                const int cand = (seg << 4) + __popcll(b2) - 1;  // >= seg*16
                const int cval = __shfl(v2, cand & 15);
                if (cval == tok)
                    s = train_weight + (size_t)cand * EMBED_DIM;
            }
            src[t] = s;
        }
    } else {
        // Generic fallback: serial binary search per token (wave-uniform).
        #pragma unroll
        for (int t = 0; t < TPW; ++t) {
            const int tok = toks[t];
            int lo = 0, hi = num_tune;
            while (lo < hi) {
                const int mid = (lo + hi) >> 1;
                if (tune_ids[mid] <= tok) lo = mid + 1;
                else                      hi = mid;
            }
            const int cand = lo - 1;
            const float* s = base_weight + (size_t)tok * EMBED_DIM;
            if (cand >= 0 && tune_ids[cand] == tok)
                s = train_weight + (size_t)cand * EMBED_DIM;
            src[t] = s;
        }
    }

    // ---- batched read burst: 12 dwordx4 loads back-to-back (12 KB/wave) ----
    f4 r[TPW][3];
    #pragma unroll
    for (int t = 0; t < TPW; ++t) {
        if (valid[t]) {
            const f4* s4 = (const f4*)src[t];
            r[t][0] = s4[lane];
            r[t][1] = s4[lane + 64];
            r[t][2] = s4[lane + 128];
        }
    }

    // ---- batched write burst: 12 KB contiguous NT stores per wave ----
    #pragma unroll
    for (int t = 0; t < TPW; ++t) {
        if (valid[t]) {
            f4* d4 = (f4*)(out + (size_t)(tbase + t) * EMBED_DIM);
            __builtin_nontemporal_store(r[t][0], d4 + lane);
            __builtin_nontemporal_store(r[t][1], d4 + lane + 64);
            __builtin_nontemporal_store(r[t][2], d4 + lane + 128);
        }
    }
}

extern "C" void kernel_launch(void* const* d_in, const int* in_sizes, int n_in,
                              void* d_out, int out_size, void* d_ws, size_t ws_size,
                              hipStream_t stream) {
    const int*   input_ids    = (const int*)d_in[0];
    const int*   tune_ids     = (const int*)d_in[1];
    const float* base_weight  = (const float*)d_in[2];
    const float* train_weight = (const float*)d_in[3];
    float*       out          = (float*)d_out;

    const int num_tokens = in_sizes[0];   // 8 * 4096 = 32768
    const int num_tune   = in_sizes[1];   // 1024

    const int grid = (num_tokens + TOKENS_PER_BLOCK - 1) / TOKENS_PER_BLOCK;
    split_embedding_kernel<<<grid, BLOCK_THREADS, 0, stream>>>(
        input_ids, tune_ids, base_weight, train_weight, out, num_tokens, num_tune);
}